// Round 8
// baseline (63.272 us; speedup 1.0000x reference)
//
#include <hip/hip_runtime.h>

typedef int   i32x4  __attribute__((ext_vector_type(4)));
typedef int   i32x8  __attribute__((ext_vector_type(8)));
typedef float f32x16 __attribute__((ext_vector_type(16)));

#define B_ROWS 4096
#define NROWS  8192
#define DDIM   512
// exp(sim/T) = exp2(sim * (1/T)/ln2), T=0.5 -> 2/ln2
#define SCALE2 2.8853900817779268f
// e8m0 scale 127 = 2^0 = 1.0 in every byte -> scaled MFMA == plain fp8 MFMA
#define SCL1   0x7f7f7f7f

// zq layout (v2, unchanged, verified R2/R3): per 32-row group (rg32 = row>>5),
// 16 KB = 8 k-groups (kg = k>>6) x 2 KB segments; lane l = (k>>5)*32 + (row&31)
// owns 16 B at seg+l*16 (k%32 in [0,16)) and 16 B at seg+1024+l*16.
// An MFMA A/B fragment = two LINEAR 16B loads at lane*16 / +1024.
//
// R7 proved: direct-from-L2 (no LDS staging, no barriers) is the right structure
// (53us, VALUBusy 68% = new bottleneck). R8 cuts VALU: (1) uniform-base +
// 32-bit-voffset addressing -> saddr loads, SALU uniform math, 1 VGPR per
// pending address; (2) union i32x8 assembly (no repack movs); (3) epilogue
// specialized clean/diag/pos (95% of blocks: mul+exp+add only); (4) raw
// v_exp_f32 via builtin (|x| <= 3.1, no OCML fixup needed).
//
// scratch (R3 scheme): 64x64 grid of 128-float cells, each written EXACTLY once
// (row-parts of block (bi,bj) -> cell (bi,bj); col-parts -> cell (bj,bi)).

// ---------------- normalize: fp32 -> fp8 e4m3, 32-row blocks, LDS-repack ---------
__global__ __launch_bounds__(256) void normalize_kernel(
    const float* __restrict__ h1, const float* __restrict__ h2,
    unsigned char* __restrict__ zq, float* __restrict__ out) {
  __shared__ __align__(16) unsigned char tile[16384];
  if (blockIdx.x == 0 && threadIdx.x == 0) out[0] = 0.0f;

  const int wave = threadIdx.x >> 6;
  const int lane = threadIdx.x & 63;
  const int rb = blockIdx.x;            // 32-row group
  // lane covers k = lane*8 .. lane*8+7
  const int kg = lane >> 3;             // k-group of 64
  const int q  = (lane >> 1) & 1;       // (k>>4)&1: which 16B half-page
  const int h  = (lane >> 2) & 1;       // (k>>5)&1: k-half of 32 (lane-id bit 5)
  const int k8 = (lane & 1) * 8;        // (k&15) byte offset within 16B unit

  #pragma unroll
  for (int it = 0; it < 8; ++it) {
    const int r = it * 4 + wave;        // 0..31, one full row per wave
    const int row = rb * 32 + r;
    const float* src = (row < B_ROWS) ? (h1 + (size_t)row * DDIM)
                                      : (h2 + (size_t)(row - B_ROWS) * DDIM);
    float4 v0 = *(const float4*)(src + lane * 8);
    float4 v1 = *(const float4*)(src + lane * 8 + 4);
    float ss = v0.x*v0.x + v0.y*v0.y + v0.z*v0.z + v0.w*v0.w
             + v1.x*v1.x + v1.y*v1.y + v1.z*v1.z + v1.w*v1.w;
    #pragma unroll
    for (int m = 1; m <= 32; m <<= 1) ss += __shfl_xor(ss, m);
    float sc = 1.0f / fmaxf(sqrtf(ss), 1e-8f);
    int lo = 0, hi = 0;
    lo = __builtin_amdgcn_cvt_pk_fp8_f32(v0.x*sc, v0.y*sc, lo, 0);
    lo = __builtin_amdgcn_cvt_pk_fp8_f32(v0.z*sc, v0.w*sc, lo, 1);
    hi = __builtin_amdgcn_cvt_pk_fp8_f32(v1.x*sc, v1.y*sc, hi, 0);
    hi = __builtin_amdgcn_cvt_pk_fp8_f32(v1.z*sc, v1.w*sc, hi, 1);
    *(int2*)(tile + kg * 2048 + q * 1024 + (h * 32 + r) * 16 + k8) =
        make_int2(lo, hi);
  }
  __syncthreads();
  const size_t base = (size_t)rb * 16384;
  #pragma unroll
  for (int j = 0; j < 4; ++j)
    *(int4*)(zq + base + j * 4096 + threadIdx.x * 16) =
        *(const int4*)(tile + j * 4096 + threadIdx.x * 16);
}

// ---------------- fused sim GEMM (MX-fp8, direct-from-L2) + exp + row-sum --------
union U8 { i32x8 v; i32x4 h[2]; };

__global__ __launch_bounds__(256, 3) void simexp_kernel(
    const unsigned char* __restrict__ zq, float* __restrict__ scratch,
    float* __restrict__ pos) {
  __shared__ float rp[256];   // row partials: slot lrow*2 + wn
  __shared__ float cp[256];   // col partials: slot lcol*2 + wm

  const int tid  = threadIdx.x;
  const int wave = tid >> 6;
  const int lane = tid & 63;
  const int wm = wave >> 1, wn = wave & 1;
  const int l31 = lane & 31;
  const int hi5 = lane >> 5;

  // unrank triangular block index: t = bi*(bi+1)/2 + bj, bi >= bj
  int t  = blockIdx.x;
  int bi = (int)((sqrtf(8.0f * (float)t + 1.0f) - 1.0f) * 0.5f);
  while ((bi + 1) * (bi + 2) / 2 <= t) ++bi;
  while (bi * (bi + 1) / 2 > t) --bi;
  int bj = t - bi * (bi + 1) / 2;
  const int rowBlk = bi * 128;
  const int colBlk = bj * 128;
  const bool isDiag = (bi == bj);
  const bool posBlk = (bi - bj == 32);  // contains the +B diagonal

  // 32-bit voffsets from the uniform zq base -> saddr-form loads.
  // A rows: rg32 = bi*4 + wm*2 + rt ; B cols: rg32 = bj*4 + wn*2 + ct
  const unsigned int vbaseA =
      (unsigned int)bi * 65536u + (unsigned int)wm * 32768u + (unsigned int)lane * 16u;
  const unsigned int vbaseB =
      (unsigned int)bj * 65536u + (unsigned int)wn * 32768u + (unsigned int)lane * 16u;

  f32x16 acc[2][2] = {};

  #pragma unroll
  for (int kk = 0; kk < 8; ++kk) {           // K-64 step; no barriers anywhere
    U8 afr[2], bfr[2];
    #pragma unroll
    for (int rt = 0; rt < 2; ++rt) {
      const unsigned char* p = zq + (vbaseA + (unsigned)rt * 16384u + (unsigned)kk * 2048u);
      afr[rt].h[0] = *(const i32x4*)p;
      afr[rt].h[1] = *(const i32x4*)(p + 1024);
    }
    #pragma unroll
    for (int ct = 0; ct < 2; ++ct) {
      const unsigned char* p = zq + (vbaseB + (unsigned)ct * 16384u + (unsigned)kk * 2048u);
      bfr[ct].h[0] = *(const i32x4*)p;
      bfr[ct].h[1] = *(const i32x4*)(p + 1024);
    }
    #pragma unroll
    for (int rt = 0; rt < 2; ++rt)
      #pragma unroll
      for (int ct = 0; ct < 2; ++ct)
        acc[rt][ct] = __builtin_amdgcn_mfma_scale_f32_32x32x64_f8f6f4(
            afr[rt].v, bfr[ct].v, acc[rt][ct], 0, 0, 0, SCL1, 0, SCL1);
  }

  // ---- epilogue: exp2 in place (specialized) -> butterfly row-reduce -> stores ----
  // 32x32 C/D layout: col = lane&31, row = (reg&3) + 8*(reg>>2) + 4*(lane>>5)
  float colpart[2] = {0.f, 0.f};

  auto body = [&](bool DIAG, bool POSB) __attribute__((always_inline)) {
    #pragma unroll
    for (int rt = 0; rt < 2; ++rt)
      #pragma unroll
      for (int ct = 0; ct < 2; ++ct)
        #pragma unroll
        for (int reg = 0; reg < 16; ++reg) {
          float sv = acc[rt][ct][reg];
          float e = __builtin_amdgcn_exp2f(sv * SCALE2);
          if (DIAG || POSB) {
            const int lrow = wm * 64 + rt * 32 + (reg & 3) + 8 * (reg >> 2) + 4 * hi5;
            const int grow = rowBlk + lrow;
            const int gcol = colBlk + wn * 64 + ct * 32 + l31;
            if (DIAG && grow == gcol) e = 0.f;
            if (POSB && grow - B_ROWS == gcol) pos[gcol] = sv;
          }
          acc[rt][ct][reg] = e;
          colpart[ct] += e;
        }
  };
  if (isDiag)       body(true, false);
  else if (posBlk)  body(false, true);
  else              body(false, false);   // 1984 of 2080 blocks: mul+exp+add only

  // row sums: per rt, 16 values (ct-pairs pre-added) over 32 lanes in 16 shfl.
  // After the butterfly, lane l31 holds the row-sum for
  //   reg16 = 8*(l&1) + 4*((l>>1)&1) + 2*((l>>2)&1) + ((l>>3)&1)
  #pragma unroll
  for (int rt = 0; rt < 2; ++rt) {
    float v[16];
    #pragma unroll
    for (int reg = 0; reg < 16; ++reg)
      v[reg] = acc[rt][0][reg] + acc[rt][1][reg];   // same row, cols +-32
    #pragma unroll
    for (int st = 0; st < 4; ++st) {
      const int m = 1 << st;
      const int n = 8 >> st;
      #pragma unroll
      for (int i = 0; i < n; ++i) {
        float send = (l31 & m) ? v[i] : v[i + n];
        float keep = (l31 & m) ? v[i + n] : v[i];
        v[i] = keep + __shfl_xor(send, m);
      }
    }
    v[0] += __shfl_xor(v[0], 16);                   // same reg16 both sides
    const int reg16 = 8 * (l31 & 1) + 4 * ((l31 >> 1) & 1)
                    + 2 * ((l31 >> 2) & 1) + ((l31 >> 3) & 1);
    const int lrow = wm * 64 + rt * 32 + (reg16 & 3) + 8 * (reg16 >> 2) + 4 * hi5;
    if (l31 < 16) rp[lrow * 2 + wn] = v[0];         // single writer per slot
  }
  #pragma unroll
  for (int ct = 0; ct < 2; ++ct) {
    float c = colpart[ct];
    c += __shfl_xor(c, 32);                         // combine hi5 halves, same col
    if (hi5 == 0) cp[(wn * 64 + ct * 32 + l31) * 2 + wm] = c;  // single writer
  }
  __syncthreads();
  if (tid < 128) {
    scratch[(size_t)(bi * 64 + bj) * 128 + tid] = rp[tid * 2] + rp[tid * 2 + 1];
  } else if (!isDiag) {
    const int c = tid - 128;
    scratch[(size_t)(bj * 64 + bi) * 128 + c] = cp[c * 2] + cp[c * 2 + 1];
  }
}

// ---------------- finalize: rowsum from scratch; loss mean ------------------------
__global__ __launch_bounds__(256) void finalize_kernel(
    const float* __restrict__ scratch, const float* __restrict__ pos,
    float* __restrict__ out) {
  __shared__ float red[4];
  const int gid = blockIdx.x * 256 + threadIdx.x;
  const int band = gid >> 7, r = gid & 127;
  const float* base = scratch + (size_t)band * 64 * 128 + r;
  float s = 0.f;
  #pragma unroll 8
  for (int c = 0; c < 64; ++c) s += base[c * 128];
  float loss = __logf(s) - 2.0f * pos[gid & (B_ROWS - 1)];
  #pragma unroll
  for (int m = 1; m <= 32; m <<= 1) loss += __shfl_xor(loss, m);
  const int wave = threadIdx.x >> 6;
  const int lane = threadIdx.x & 63;
  if (lane == 0) red[wave] = loss;
  __syncthreads();
  if (threadIdx.x == 0)
    atomicAdd(out, (red[0] + red[1] + red[2] + red[3]) * (1.0f / NROWS));
}

extern "C" void kernel_launch(void* const* d_in, const int* in_sizes, int n_in,
                              void* d_out, int out_size, void* d_ws, size_t ws_size,
                              hipStream_t stream) {
  const float* h1 = (const float*)d_in[0];
  const float* h2 = (const float*)d_in[1];
  float* out = (float*)d_out;
  unsigned char* zq = (unsigned char*)d_ws;                        // 4 MiB fp8
  float* scratch = (float*)((char*)d_ws + (size_t)NROWS * DDIM);   // 2 MiB
  float* pos     = scratch + 64 * 64 * 128;                        // 16 KiB

  normalize_kernel<<<NROWS / 32, 256, 0, stream>>>(h1, h2, zq, out);
  simexp_kernel<<<64 * 65 / 2, 256, 0, stream>>>(zq, scratch, pos);
  finalize_kernel<<<NROWS / 256, 256, 0, stream>>>(scratch, pos, out);
}